// Round 10
// baseline (229.642 us; speedup 1.0000x reference)
//
#include <hip/hip_runtime.h>
#include <hip/hip_bf16.h>

// B=2048, N=512, D=8192.
// Pipeline (NO d_ws, NO atomics; scratch carved from d_out, per-block ownership):
//   1. m_norms:     mm[n]=||m_n||^2 -> p-slot (dead after rescore)
//   2. gemm_coarse: bf16 MFMA dot partials, 128x128 tile, splitK=8 -> m+sd (32 MB).
//                   512-thread blocks, DOUBLE-BUFFERED LDS staging: loads for
//                   step+1 issued before compute of step (r9 profile: 78% stall,
//                   loads were issued-then-barriered with zero within-block
//                   overlap). LDS 64 KB is free: grid 512 = 2 blocks/CU anyway.
//   3. rescore:     coarse argmin + margin candidates; exact f32 dots only if >=2
//                   candidates, candidate-per-wave; index-ordered winner scan.
//   4. ema_scatter: grid (N,8); block (n,s) owns 1024-float slice s; wave 0
//                   ballot-builds ordered list; 16x batched gathers (predicated
//                   final batch), exact-order EMA.

#define Bb 2048
#define Nn 512
#define Dd 8192
#define MARGIN 12.0f
#define KC 8
#define KSTEPS 32   // (Dd/KC)/32

typedef __attribute__((ext_vector_type(4))) float f32x4;
typedef __attribute__((ext_vector_type(8))) short s16x8;

union Frag { unsigned u[4]; s16x8 s; };

__device__ inline unsigned pack2(float lo, float hi) {
    return __builtin_amdgcn_perm(__float_as_uint(hi), __float_as_uint(lo), 0x07060302u);
}

__device__ inline void ema4(float4& mcv, float4& scv, const float4 yv) {
#define EMA_C(c) { mcv.c = mcv.c * 0.001f + yv.c * 0.999f; \
                   float d_ = mcv.c - yv.c;                 \
                   scv.c = d_ * d_ * 0.001f + scv.c * 0.999f; }
    EMA_C(x) EMA_C(y) EMA_C(z) EMA_C(w)
#undef EMA_C
}

// ---------------- 1: m row norms ----------------
__global__ __launch_bounds__(256) void m_norms(const float* __restrict__ M,
                                               float* __restrict__ mm) {
    int n = blockIdx.x, t = threadIdx.x;
    const float4* r = (const float4*)(M + (size_t)n * Dd);
    float s = 0.f;
#pragma unroll
    for (int u = 0; u < 8; u++) {
        float4 v = r[t + 256 * u];
        s += v.x * v.x + v.y * v.y + v.z * v.z + v.w * v.w;
    }
    __shared__ float red[256];
    red[t] = s;
    __syncthreads();
    for (int off = 128; off > 0; off >>= 1) {
        if (t < off) red[t] += red[t + off];
        __syncthreads();
    }
    if (t == 0) mm[n] = red[0];
}

// ---------------- 2: coarse bf16 MFMA GEMM (dot only), splitK=8, dbuf ----------
// grid (4 coltiles, 16 rowtiles, 8 kchunks) = 512 blocks (2/CU), 512 threads.
// Tile 128x128, K-chunk 1024 (32 steps of 32). Wave w: rows (w&3)*32..+31,
// cols (w>>2)*64..+63. f32 staged via global_load_lds + XOR seg-swizzle into
// alternating LDS buffers; next-step loads issued BEFORE current-step compute.
__global__ __launch_bounds__(512, 4) void gemm_coarse(const float* __restrict__ Y,
                                                      const float* __restrict__ M,
                                                      float* __restrict__ part) {
    __shared__ __align__(16) float As[2][128 * 32];   // 32 KB
    __shared__ __align__(16) float Bs[2][128 * 32];   // 32 KB
    const int t = threadIdx.x;
    const int lane = t & 63;
    const int w = t >> 6;
    const int ct = blockIdx.x, rt = blockIdx.y, kc = blockIdx.z;

    const size_t ybase = (size_t)rt * 128 * Dd + (size_t)kc * (KSTEPS * 32);
    const size_t mbase = (size_t)ct * 128 * Dd + (size_t)kc * (KSTEPS * 32);

    // staging map: instr u of wave w covers flat = (w*2+u)*64 + lane  (1024 slots)
    int rowS[2], soff[2];
#pragma unroll
    for (int u = 0; u < 2; u++) {
        int flat = (w * 2 + u) * 64 + lane;
        int row = flat >> 3, seg = flat & 7;
        rowS[u] = row;
        soff[u] = (seg ^ (row & 7)) * 4;
    }

#define STAGE(buf, kpos)                                                          \
    {                                                                             \
        _Pragma("unroll")                                                         \
        for (int u = 0; u < 2; u++) {                                             \
            const float* gA = Y + ybase + (size_t)rowS[u] * Dd + (kpos) + soff[u];\
            const float* gB = M + mbase + (size_t)rowS[u] * Dd + (kpos) + soff[u];\
            __builtin_amdgcn_global_load_lds(                                     \
                (const __attribute__((address_space(1))) void*)gA,                \
                (__attribute__((address_space(3))) void*)(As[buf] + (w * 2 + u) * 256), 16, 0, 0); \
            __builtin_amdgcn_global_load_lds(                                     \
                (const __attribute__((address_space(1))) void*)gB,                \
                (__attribute__((address_space(3))) void*)(Bs[buf] + (w * 2 + u) * 256), 16, 0, 0); \
        }                                                                         \
    }

    const int wr0 = (w & 3) * 32, wc0 = (w >> 2) * 64;
    const int l15 = lane & 15, quad = lane >> 4;

    f32x4 acc[2][4];
#pragma unroll
    for (int i = 0; i < 2; i++)
#pragma unroll
        for (int j = 0; j < 4; j++) acc[i][j] = (f32x4)(0.0f);

    STAGE(0, 0);
    __syncthreads();

    for (int step = 0; step < KSTEPS; step++) {
        const int cur = step & 1;
        if (step + 1 < KSTEPS) STAGE(cur ^ 1, (step + 1) * 32);  // prefetch overlaps compute

        const float* Acur = As[cur];
        const float* Bcur = Bs[cur];
        Frag fa[2], fb[4];
#pragma unroll
        for (int ta = 0; ta < 2; ta++) {
            int rowa = wr0 + ta * 16 + l15;
            const float* Ar = Acur + rowa * 32;
            int s0 = ((quad * 2) ^ (rowa & 7)) * 4;
            int s1 = ((quad * 2 + 1) ^ (rowa & 7)) * 4;
            f32x4 x0 = *(const f32x4*)(Ar + s0);
            f32x4 x1 = *(const f32x4*)(Ar + s1);
            fa[ta].u[0] = pack2(x0[0], x0[1]);
            fa[ta].u[1] = pack2(x0[2], x0[3]);
            fa[ta].u[2] = pack2(x1[0], x1[1]);
            fa[ta].u[3] = pack2(x1[2], x1[3]);
        }
#pragma unroll
        for (int tb = 0; tb < 4; tb++) {
            int rowb = wc0 + tb * 16 + l15;
            const float* Br = Bcur + rowb * 32;
            int s0 = ((quad * 2) ^ (rowb & 7)) * 4;
            int s1 = ((quad * 2 + 1) ^ (rowb & 7)) * 4;
            f32x4 x0 = *(const f32x4*)(Br + s0);
            f32x4 x1 = *(const f32x4*)(Br + s1);
            fb[tb].u[0] = pack2(x0[0], x0[1]);
            fb[tb].u[1] = pack2(x0[2], x0[3]);
            fb[tb].u[2] = pack2(x1[0], x1[1]);
            fb[tb].u[3] = pack2(x1[2], x1[3]);
        }
#pragma unroll
        for (int i = 0; i < 2; i++)
#pragma unroll
            for (int j = 0; j < 4; j++)
                acc[i][j] = __builtin_amdgcn_mfma_f32_16x16x32_bf16(fa[i].s, fb[j].s, acc[i][j], 0, 0, 0);
        __syncthreads();   // waves done reading cur; prefetch into cur^1 drained
    }
#undef STAGE

    // store partials; C/D layout: col = lane&15, row = quad*4 + reg
    float* P = part + (size_t)kc * (Bb * Nn);
#pragma unroll
    for (int i = 0; i < 2; i++) {
        int rg = rt * 128 + wr0 + i * 16 + quad * 4;
#pragma unroll
        for (int j = 0; j < 4; j++) {
            int cg = ct * 128 + wc0 + j * 16 + l15;
#pragma unroll
            for (int r = 0; r < 4; r++)
                P[(size_t)(rg + r) * Nn + cg] = acc[i][j][r];
        }
    }
}

// ---------------- 3: coarse argmin + wave-parallel exact rescore ----------------
__global__ __launch_bounds__(256) void rescore(const float* __restrict__ Y,
                                               const float* __restrict__ M,
                                               const float* __restrict__ part,
                                               const float* __restrict__ mm,
                                               float* __restrict__ assignF) {
    __shared__ float redW[4];
    __shared__ int candList[Nn];
    __shared__ float candD2[Nn];
    __shared__ int candCnt;
    int b = blockIdx.x, t = threadIdx.x, lane = t & 63, w = t >> 6;
    if (t == 0) candCnt = 0;

    int c0 = t, c1 = t + 256;
    float dot0 = 0.f, dot1 = 0.f;
#pragma unroll
    for (int k = 0; k < KC; k++) {
        dot0 += part[(size_t)k * (Bb * Nn) + (size_t)b * Nn + c0];
        dot1 += part[(size_t)k * (Bb * Nn) + (size_t)b * Nn + c1];
    }
    float d0 = mm[c0] - 2.0f * dot0;
    float d1 = mm[c1] - 2.0f * dot1;

    float mn = fminf(d0, d1);
#pragma unroll
    for (int off = 32; off > 0; off >>= 1) mn = fminf(mn, __shfl_xor(mn, off));
    if (lane == 0) redW[w] = mn;
    __syncthreads();
    float thresh = fminf(fminf(redW[0], redW[1]), fminf(redW[2], redW[3])) + MARGIN;

    if (d0 <= thresh) candList[atomicAdd(&candCnt, 1)] = c0;
    if (d1 <= thresh) candList[atomicAdd(&candCnt, 1)] = c1;
    __syncthreads();
    int ncand = candCnt;

    if (ncand == 1) {                 // uncontested coarse winner: exact dot unnecessary
        if (t == 0) assignF[b] = (float)candList[0];
        return;
    }

    // each wave handles candidates j = w, w+4, ... (full-row dot per wave)
    const float4* yr = (const float4*)(Y + (size_t)b * Dd);
    for (int j = w; j < ncand; j += 4) {
        int c = candList[j];
        const float4* mr = (const float4*)(M + (size_t)c * Dd);
        float p = 0.f;
#pragma unroll 8
        for (int u = 0; u < 32; u++) {
            float4 yv = yr[u * 64 + lane];
            float4 mv = mr[u * 64 + lane];
            p += yv.x * mv.x + yv.y * mv.y + yv.z * mv.z + yv.w * mv.w;
        }
#pragma unroll
        for (int off = 32; off > 0; off >>= 1) p += __shfl_xor(p, off);
        if (lane == 0) candD2[j] = mm[c] - 2.0f * p;
    }
    __syncthreads();

    if (t == 0) {       // index-ordered scan: deterministic regardless of list order
        float bestV = 3.4e38f;
        int bestI = 0x3fffffff;
        for (int j = 0; j < ncand; j++) {
            float d2e = candD2[j];
            int c = candList[j];
            if (d2e < bestV || (d2e == bestV && c < bestI)) { bestV = d2e; bestI = c; }
        }
        assignF[b] = (float)bestI;
    }
}

// ---------------- 4: per-cluster sequential EMA, D-sliced x8, fused list build ----
__global__ __launch_bounds__(256) void ema_scatter(const float* __restrict__ Y,
                                                   const float* __restrict__ M0,
                                                   const float* __restrict__ SD0,
                                                   const float* __restrict__ P0,
                                                   const float* __restrict__ assignF,
                                                   float* __restrict__ m_out,
                                                   float* __restrict__ sd_out,
                                                   float* __restrict__ p_out) {
    __shared__ int lst[Bb];
    __shared__ int cntSh;
    int n = blockIdx.x, s = blockIdx.y, t = threadIdx.x, lane = t & 63, w = t >> 6;

    if (w == 0) {       // wave 0 ballot-scans the assignments into an ordered list
        int cnt = 0;
#pragma unroll
        for (int u = 0; u < 32; u++) {
            int zi = (int)assignF[u * 64 + lane];
            unsigned long long mask = __ballot(zi == n);
            if (zi == n) lst[cnt + (int)__popcll(mask & ((1ull << lane) - 1ull))] = u * 64 + lane;
            cnt += (int)__popcll(mask);
        }
        if (lane == 0) {
            cntSh = cnt;
            if (s == 0) p_out[n] = P0[n] + (float)cnt;
        }
    }
    __syncthreads();
    int cnt = cntSh;

    size_t off = (size_t)n * Dd + (size_t)s * 1024;
    float4 mc = *(const float4*)(M0 + off + 4 * t);
    float4 sc = *(const float4*)(SD0 + off + 4 * t);

    // 16x batched gathers; final batch predicated (index clamped, apply guarded)
    for (int base = 0; base < cnt; base += 16) {
        float4 yv[16];
#pragma unroll
        for (int q = 0; q < 16; q++) {
            int jj = base + q;
            int idx = lst[jj < cnt ? jj : cnt - 1];
            yv[q] = *(const float4*)(Y + (size_t)idx * Dd + (size_t)s * 1024 + 4 * t);
        }
#pragma unroll
        for (int q = 0; q < 16; q++)
            if (base + q < cnt) ema4(mc, sc, yv[q]);
    }

    *(float4*)(m_out + off + 4 * t) = mc;
    *(float4*)(sd_out + off + 4 * t) = sc;
}

extern "C" void kernel_launch(void* const* d_in, const int* in_sizes, int n_in,
                              void* d_out, int out_size, void* d_ws, size_t ws_size,
                              hipStream_t stream) {
    const float* y  = (const float*)d_in[0];
    const float* m  = (const float*)d_in[1];
    const float* sd = (const float*)d_in[2];
    const float* p  = (const float*)d_in[3];

    float* out     = (float*)d_out;
    float* m_out   = out;                       // partials k=0..3 live here pre-rescore
    float* sd_out  = out + 4194304;             // partials k=4..7 live here pre-rescore
    float* p_out   = out + 8388608;             // also: mm norms (dead after rescore)
    float* assignF = out + 8389120;
    float* part    = out;                       // 8 x 1M floats = m+sd regions exactly

    m_norms    <<<Nn, 256, 0, stream>>>(m, p_out);
    gemm_coarse<<<dim3(4, 16, KC), 512, 0, stream>>>(y, m, part);
    rescore    <<<Bb, 256, 0, stream>>>(y, m, part, p_out, assignF);
    ema_scatter<<<dim3(Nn, 8), 256, 0, stream>>>(y, m, sd, p, assignF, m_out, sd_out, p_out);
}